// Round 2
// baseline (1804.221 us; speedup 1.0000x reference)
//
#include <hip/hip_runtime.h>
#include <cstddef>

typedef __attribute__((ext_vector_type(4))) int   i32x4;
typedef __attribute__((ext_vector_type(8))) unsigned short us8;

__device__ inline unsigned short f2bf(float x){
  union { float f; unsigned u; } v; v.f = x;
  unsigned r = v.u + 0x7fffu + ((v.u >> 16) & 1u);
  return (unsigned short)(r >> 16);
}
__device__ inline float bf2f(unsigned short u){
  union { unsigned u; float f; } v; v.u = ((unsigned)u) << 16; return v.f;
}
__device__ inline float fsig(float x){ return 1.f / (1.f + __expf(-x)); }
__device__ inline float ftanhf(float x){ return 2.f / (1.f + __expf(-2.f * x)) - 1.f; }

#define SW 0.30f   // int8 scale for w_hh: w = q * (SW/127)

// ---------------- conv1: [2048,4,84,84] -> relu -> bf16 [2048,16,20,20], k=8 s=4 ----------------
__global__ __launch_bounds__(512) void conv1_k(const float* __restrict__ obs,
                                               const float* __restrict__ w,
                                               const float* __restrict__ b,
                                               unsigned short* __restrict__ out){
  __shared__ __align__(16) float s_img[28224];   // 4*84*84
  __shared__ __align__(16) float s_w[4096];      // 16*256
  __shared__ float s_b[16];
  const int n = blockIdx.x, tid = threadIdx.x;
  {
    const float4* src = (const float4*)(obs + (size_t)n * 28224);
    float4* d = (float4*)s_img;
    for (int i = tid; i < 7056; i += 512) d[i] = src[i];
    const float4* ws = (const float4*)w;
    float4* dw = (float4*)s_w;
    for (int i = tid; i < 1024; i += 512) dw[i] = ws[i];
    if (tid < 16) s_b[tid] = b[tid];
  }
  __syncthreads();
  const int lane = tid & 63, wave = tid >> 6;
  const int cg = wave & 3;   // channels 4cg..4cg+3
  const int pg = wave >> 2;  // position group 0/1
  float acc[4][4];
  #pragma unroll
  for (int r = 0; r < 4; ++r)
    #pragma unroll
    for (int c = 0; c < 4; ++c) acc[r][c] = 0.f;
  int p[4], py[4], px[4]; bool valid[4];
  #pragma unroll
  for (int r = 0; r < 4; ++r){
    int pp = pg * 64 + lane + r * 128;
    valid[r] = pp < 400;
    if (pp > 399) pp = 399;
    p[r] = pp; py[r] = pp / 20; px[r] = pp % 20;
  }
  for (int ci = 0; ci < 4; ++ci){
    #pragma unroll
    for (int ky = 0; ky < 8; ++ky){
      float4 wv[4][2];
      #pragma unroll
      for (int c = 0; c < 4; ++c){
        const float4* wp = (const float4*)&s_w[(cg * 4 + c) * 256 + ci * 64 + ky * 8];
        wv[c][0] = wp[0]; wv[c][1] = wp[1];
      }
      #pragma unroll
      for (int r = 0; r < 4; ++r){
        const float4* ip = (const float4*)&s_img[ci * 7056 + (4 * py[r] + ky) * 84 + 4 * px[r]];
        float4 a0 = ip[0], a1 = ip[1];
        #pragma unroll
        for (int c = 0; c < 4; ++c){
          acc[r][c] += a0.x * wv[c][0].x + a0.y * wv[c][0].y + a0.z * wv[c][0].z + a0.w * wv[c][0].w
                     + a1.x * wv[c][1].x + a1.y * wv[c][1].y + a1.z * wv[c][1].z + a1.w * wv[c][1].w;
        }
      }
    }
  }
  unsigned short* op = out + (size_t)n * 6400;
  #pragma unroll
  for (int r = 0; r < 4; ++r) if (valid[r]){
    #pragma unroll
    for (int c = 0; c < 4; ++c){
      float v = acc[r][c] + s_b[cg * 4 + c];
      op[(cg * 4 + c) * 400 + p[r]] = f2bf(v > 0.f ? v : 0.f);
    }
  }
}

// ---------------- conv2: bf16 [2048,16,20,20] -> relu -> flat fp32 [2048, 32*81], k=4 s=2 ----------------
__global__ __launch_bounds__(256) void conv2_k(const unsigned short* __restrict__ in,
                                               const float* __restrict__ w,
                                               const float* __restrict__ b,
                                               float* __restrict__ out){
  __shared__ __align__(16) float s_in[6400];   // 16*400
  __shared__ __align__(16) float s_w[8192];    // 32*256
  __shared__ float s_b[32];
  const int n = blockIdx.x, tid = threadIdx.x;
  {
    const us8* src = (const us8*)(in + (size_t)n * 6400);
    for (int i = tid; i < 800; i += 256){
      us8 v = src[i];
      #pragma unroll
      for (int j = 0; j < 8; ++j) s_in[i * 8 + j] = bf2f(v[j]);
    }
    const float4* ws = (const float4*)w;
    float4* dw = (float4*)s_w;
    for (int i = tid; i < 2048; i += 256) dw[i] = ws[i];
    if (tid < 32) s_b[tid] = b[tid];
  }
  __syncthreads();
  const int lane = tid & 63, wave = tid >> 6;  // wave handles channels 8w..8w+7
  float acc[2][8];
  #pragma unroll
  for (int r = 0; r < 2; ++r)
    #pragma unroll
    for (int c = 0; c < 8; ++c) acc[r][c] = 0.f;
  const int p0 = lane;
  int p1 = lane + 64; const bool v1 = p1 < 81; if (p1 > 80) p1 = 80;
  const int y0 = p0 / 9, x0 = p0 % 9, y1 = p1 / 9, x1 = p1 % 9;
  for (int ci = 0; ci < 16; ++ci){
    #pragma unroll
    for (int ky = 0; ky < 4; ++ky){
      float4 wv[8];
      #pragma unroll
      for (int c = 0; c < 8; ++c)
        wv[c] = *(const float4*)&s_w[(wave * 8 + c) * 256 + ci * 16 + ky * 4];
      const float2 a0  = *(const float2*)&s_in[ci * 400 + (2 * y0 + ky) * 20 + 2 * x0];
      const float2 a0b = *(const float2*)&s_in[ci * 400 + (2 * y0 + ky) * 20 + 2 * x0 + 2];
      const float2 a1  = *(const float2*)&s_in[ci * 400 + (2 * y1 + ky) * 20 + 2 * x1];
      const float2 a1b = *(const float2*)&s_in[ci * 400 + (2 * y1 + ky) * 20 + 2 * x1 + 2];
      #pragma unroll
      for (int c = 0; c < 8; ++c){
        acc[0][c] += a0.x * wv[c].x + a0.y * wv[c].y + a0b.x * wv[c].z + a0b.y * wv[c].w;
        acc[1][c] += a1.x * wv[c].x + a1.y * wv[c].y + a1b.x * wv[c].z + a1b.y * wv[c].w;
      }
    }
  }
  float* op = out + (size_t)n * 2592;
  #pragma unroll
  for (int c = 0; c < 8; ++c){
    float v0 = acc[0][c] + s_b[wave * 8 + c];
    op[(wave * 8 + c) * 81 + p0] = v0 > 0.f ? v0 : 0.f;
    if (v1){
      float vv = acc[1][c] + s_b[wave * 8 + c];
      op[(wave * 8 + c) * 81 + p1] = vv > 0.f ? vv : 0.f;
    }
  }
}

// ---------------- generic fp32 GEMM: out[M,N] = A[M,K] @ Bw[N,K]^T + bias (+relu) ----------------
template<int RELU>
__global__ __launch_bounds__(256) void gemm_k(const float* __restrict__ A,
                                              const float* __restrict__ Bw,
                                              const float* __restrict__ bias1,
                                              const float* __restrict__ bias2,
                                              float* __restrict__ out,
                                              int M, int N, int K){
  __shared__ float As[32][33];
  __shared__ float Bs[32][65];
  const int m0 = blockIdx.x * 32, n0 = blockIdx.y * 64;
  const int tid = threadIdx.x;
  const int ty = tid >> 4, tx = tid & 15;
  float acc[2][4] = {};
  const int arow = tid >> 3, ak = (tid & 7) * 4;
  const int brow = tid >> 2, bk = (tid & 3) * 8;
  for (int k0 = 0; k0 < K; k0 += 32){
    float4 av = *(const float4*)(A + (size_t)(m0 + arow) * K + k0 + ak);
    As[arow][ak + 0] = av.x; As[arow][ak + 1] = av.y; As[arow][ak + 2] = av.z; As[arow][ak + 3] = av.w;
    float4 b0 = *(const float4*)(Bw + (size_t)(n0 + brow) * K + k0 + bk);
    float4 b1 = *(const float4*)(Bw + (size_t)(n0 + brow) * K + k0 + bk + 4);
    Bs[bk + 0][brow] = b0.x; Bs[bk + 1][brow] = b0.y; Bs[bk + 2][brow] = b0.z; Bs[bk + 3][brow] = b0.w;
    Bs[bk + 4][brow] = b1.x; Bs[bk + 5][brow] = b1.y; Bs[bk + 6][brow] = b1.z; Bs[bk + 7][brow] = b1.w;
    __syncthreads();
    #pragma unroll
    for (int kk = 0; kk < 32; ++kk){
      float a0 = As[ty * 2][kk], a1 = As[ty * 2 + 1][kk];
      float bv0 = Bs[kk][tx * 4 + 0], bv1 = Bs[kk][tx * 4 + 1];
      float bv2 = Bs[kk][tx * 4 + 2], bv3 = Bs[kk][tx * 4 + 3];
      acc[0][0] += a0 * bv0; acc[0][1] += a0 * bv1; acc[0][2] += a0 * bv2; acc[0][3] += a0 * bv3;
      acc[1][0] += a1 * bv0; acc[1][1] += a1 * bv1; acc[1][2] += a1 * bv2; acc[1][3] += a1 * bv3;
    }
    __syncthreads();
  }
  #pragma unroll
  for (int r = 0; r < 2; ++r){
    int m = m0 + ty * 2 + r;
    #pragma unroll
    for (int q = 0; q < 4; ++q){
      int nn = n0 + tx * 4 + q;
      float v = acc[r][q] + bias1[nn] + (bias2 ? bias2[nn] : 0.f);
      if (RELU) v = v > 0.f ? v : 0.f;
      out[(size_t)m * N + nn] = v;
    }
  }
}

// ---------------- quantize w_hh -> int8 (packed), scale SW/127 ----------------
__global__ __launch_bounds__(256) void quantw_k(const float* __restrict__ whh,
                                                int* __restrict__ w8){
  const int i = blockIdx.x * 256 + threadIdx.x;   // one dword = 4 weights
  float4 v = ((const float4*)whh)[i];
  const float s = 127.f / SW;
  int q0 = __float2int_rn(fminf(fmaxf(v.x * s, -127.f), 127.f));
  int q1 = __float2int_rn(fminf(fmaxf(v.y * s, -127.f), 127.f));
  int q2 = __float2int_rn(fminf(fmaxf(v.z * s, -127.f), 127.f));
  int q3 = __float2int_rn(fminf(fmaxf(v.w * s, -127.f), 127.f));
  w8[i] = (q0 & 255) | ((q1 & 255) << 8) | ((q2 & 255) << 16) | ((q3 & 255) << 24);
}

// ---------------- persistent single-block LSTM scan (int8 MFMA) ----------------
// 512 threads = 8 waves, 2 waves/SIMD -> 256-VGPR budget. Wave w owns hidden units
// {16w+col, 128+16w+col} for all 4 gates. W_hh int8 lives in registers as
// mfma_i32_16x16x64_i8 B-fragments (128 VGPRs/lane). h passes through an
// XOR-swizzled int8 LDS double buffer; c and gates stay fp32 in registers.
__global__ __launch_bounds__(512, 2) void lstm_k(const float* __restrict__ gx,
                                                 const int* __restrict__ masks,
                                                 const float* __restrict__ h0,
                                                 const float* __restrict__ c0,
                                                 const int* __restrict__ w8,
                                                 float* __restrict__ feats,
                                                 float* __restrict__ out){
  __shared__ __align__(16) signed char h8[2][4096];   // [par][16 batches * 256 units]
  const int tid = threadIdx.x;
  const int w = tid >> 6, l = tid & 63;
  const int col = l & 15;          // MFMA 16-col index (unit within tile / A-row batch)
  const int rgrp = l >> 4;         // 0..3 -> batches rgrp*4..rgrp*4+3, k-block rgrp*16

  // --- B-fragments: B[k][n] = w8[grow][k], grow = nt*256 + u*128 + 16w + col ---
  i32x4 Bf[4][2][4];               // [gate nt][coltile u][ks]
  #pragma unroll
  for (int nt = 0; nt < 4; ++nt)
    #pragma unroll
    for (int u = 0; u < 2; ++u){
      const int grow = nt * 256 + u * 128 + (w << 4) + col;
      #pragma unroll
      for (int ks = 0; ks < 4; ++ks)
        Bf[nt][u][ks] = *(const i32x4*)(w8 + grow * 64 + ks * 16 + rgrp * 4);
    }

  // --- state init: lane's cells are (b = rgrp*4+r, j = u*128 + 16w + col) ---
  float c[2][4];
  float gxr[2][4][4];              // [u][nt][r]
  float mnext[4];
  const unsigned jlo = (w << 4) + col;
  const float* gxw = gx + jlo;
  #pragma unroll
  for (int r = 0; r < 4; ++r){
    const int b = (rgrp << 2) + r;
    const float m0 = (float)masks[b * 128];
    mnext[r] = (float)masks[b * 128 + 1];
    #pragma unroll
    for (int u = 0; u < 2; ++u){
      const int j = u * 128 + jlo;
      const float hv = h0[b * 256 + j] * m0;
      c[u][r] = c0[b * 256 + j] * m0;
      int q = __float2int_rn(fminf(fmaxf(hv * 127.f, -127.f), 127.f));
      h8[0][b * 256 + (j ^ ((b & 7) << 4))] = (signed char)q;
      #pragma unroll
      for (int nt = 0; nt < 4; ++nt)
        gxr[u][nt][r] = gxw[(unsigned)b * 131072u + nt * 256 + u * 128];
    }
  }
  __syncthreads();

  const float S = (SW / 127.f) * (1.f / 127.f);
  for (int t = 0; t < 128; ++t){
    const int par = t & 1;
    // A-fragments: A[m][k] = h8[m][k], m = l&15 (batch), k-block rgrp*16 within ks*64
    i32x4 Af[4];
    const signed char* hb = &h8[par][0];
    const int row = col;
    #pragma unroll
    for (int ks = 0; ks < 4; ++ks){
      const int k0 = ks * 64 + rgrp * 16;
      Af[ks] = *(const i32x4*)(hb + row * 256 + (k0 ^ ((row & 7) << 4)));
    }
    i32x4 acc[2][4];
    #pragma unroll
    for (int u = 0; u < 2; ++u)
      #pragma unroll
      for (int nt = 0; nt < 4; ++nt){
        acc[u][nt][0] = 0; acc[u][nt][1] = 0; acc[u][nt][2] = 0; acc[u][nt][3] = 0;
        #pragma unroll
        for (int ks = 0; ks < 4; ++ks)
          acc[u][nt] = __builtin_amdgcn_mfma_i32_16x16x64_i8(Af[ks], Bf[nt][u][ks], acc[u][nt], 0, 0, 0);
      }
    // elementwise: lane holds gates for (b = rgrp*4+r, j) in acc[u][0..3][r]
    float mcur[4];
    #pragma unroll
    for (int r = 0; r < 4; ++r) mcur[r] = mnext[r];
    #pragma unroll
    for (int r = 0; r < 4; ++r){
      const int b = (rgrp << 2) + r;
      const float mn = (t < 127) ? mcur[r] : 1.f;
      #pragma unroll
      for (int u = 0; u < 2; ++u){
        const int j = u * 128 + jlo;
        const float gi = (float)acc[u][0][r] * S + gxr[u][0][r];
        const float gf = (float)acc[u][1][r] * S + gxr[u][1][r];
        const float gg = (float)acc[u][2][r] * S + gxr[u][2][r];
        const float go = (float)acc[u][3][r] * S + gxr[u][3][r];
        const float iv = fsig(gi), fv = fsig(gf), gv = ftanhf(gg), ov = fsig(go);
        const float cn = fv * c[u][r] + iv * gv;
        const float hn = ov * ftanhf(cn);
        feats[((size_t)b * 128 + t) * 256 + j] = hn;
        if (t == 127){
          out[38912 + b * 256 + j] = hn;
          out[43008 + b * 256 + j] = cn;
        }
        c[u][r] = cn * mn;
        const float hm = hn * mn;
        int q = __float2int_rn(fminf(fmaxf(hm * 127.f, -127.f), 127.f));
        h8[par ^ 1][b * 256 + (j ^ ((b & 7) << 4))] = (signed char)q;
      }
    }
    // prefetch gx and masks for t+1 (consumed next step, hidden under its MFMA)
    if (t < 127){
      #pragma unroll
      for (int r = 0; r < 4; ++r){
        const int b = (rgrp << 2) + r;
        if (t < 126) mnext[r] = (float)masks[b * 128 + t + 2]; else mnext[r] = 1.f;
        const unsigned off = (unsigned)b * 131072u + (unsigned)(t + 1) * 1024u;
        #pragma unroll
        for (int u = 0; u < 2; ++u)
          #pragma unroll
          for (int nt = 0; nt < 4; ++nt)
            gxr[u][nt][r] = gxw[off + nt * 256 + u * 128];
      }
    }
    __syncthreads();
  }
}

// ---------------- heads: feats[2048,256] -> policy[2048,18], critic[2048,1] ----------------
__global__ __launch_bounds__(256) void heads_k(const float* __restrict__ feats,
                                               const float* __restrict__ pw,
                                               const float* __restrict__ pb,
                                               const float* __restrict__ cw,
                                               const float* __restrict__ cb,
                                               float* __restrict__ out){
  __shared__ float sf[64][257];
  __shared__ float swt[19][256];
  const int tid = threadIdx.x;
  const int nb = blockIdx.x * 64;
  {
    const float4* src = (const float4*)(feats + (size_t)nb * 256);
    for (int i = tid; i < 4096; i += 256){
      int rr = i >> 6, cc = (i & 63) * 4;
      float4 v = src[i];
      sf[rr][cc] = v.x; sf[rr][cc + 1] = v.y; sf[rr][cc + 2] = v.z; sf[rr][cc + 3] = v.w;
    }
    for (int i = tid; i < 1152; i += 256){
      int pp = i >> 6, cc = (i & 63) * 4;
      float4 v = ((const float4*)pw)[i];
      swt[pp][cc] = v.x; swt[pp][cc + 1] = v.y; swt[pp][cc + 2] = v.z; swt[pp][cc + 3] = v.w;
    }
    if (tid < 64){
      float4 v = ((const float4*)cw)[tid];
      int cc = tid * 4;
      swt[18][cc] = v.x; swt[18][cc + 1] = v.y; swt[18][cc + 2] = v.z; swt[18][cc + 3] = v.w;
    }
  }
  __syncthreads();
  const int n = tid & 63, pg = tid >> 6;
  float acc[5] = {0.f, 0.f, 0.f, 0.f, 0.f};
  for (int k = 0; k < 256; ++k){
    const float a = sf[n][k];
    #pragma unroll
    for (int q = 0; q < 5; ++q){
      const int p = pg + q * 4;
      if (p < 19) acc[q] += a * swt[p][k];
    }
  }
  #pragma unroll
  for (int q = 0; q < 5; ++q){
    const int p = pg + q * 4;
    if (p < 18){
      out[(size_t)(nb + n) * 18 + p] = acc[q] + pb[p];
    } else if (p == 18){
      out[36864 + nb + n] = acc[q] + cb[0];
    }
  }
}

extern "C" void kernel_launch(void* const* d_in, const int* in_sizes, int n_in,
                              void* d_out, int out_size, void* d_ws, size_t ws_size,
                              hipStream_t stream) {
  const float* obs  = (const float*)d_in[0];
  const int*   msk  = (const int*)d_in[1];
  const float* h0   = (const float*)d_in[2];
  const float* c0   = (const float*)d_in[3];
  const float* w1   = (const float*)d_in[4];
  const float* b1   = (const float*)d_in[5];
  const float* w2   = (const float*)d_in[6];
  const float* b2   = (const float*)d_in[7];
  const float* fcw  = (const float*)d_in[8];
  const float* fcb  = (const float*)d_in[9];
  const float* wih  = (const float*)d_in[10];
  const float* whh  = (const float*)d_in[11];
  const float* bih  = (const float*)d_in[12];
  const float* bhh  = (const float*)d_in[13];
  const float* pw   = (const float*)d_in[14];
  const float* pb   = (const float*)d_in[15];
  const float* cw   = (const float*)d_in[16];
  const float* cb   = (const float*)d_in[17];
  float* out = (float*)d_out;
  float* ws  = (float*)d_ws;

  // workspace layout (float offsets); peak = 11,927,552 floats = 47.7 MB
  unsigned short* c1o = (unsigned short*)ws;        // 2048*6400 bf16 = 6,553,600 floats
  float* c2o    = ws + 6553600;                     // 2048*2592
  int*   w8     = (int*)(ws + 11862016);            // 1024*256 int8 = 65,536 floats
  float* feat   = ws;                               // 2048*256 (overlays dead c1o)
  float* gatesx = ws + 524288;                      // 2048*1024
  float* feats  = ws + 2621440;                     // 2048*256

  conv1_k<<<2048, 512, 0, stream>>>(obs, w1, b1, c1o);
  conv2_k<<<2048, 256, 0, stream>>>(c1o, w2, b2, c2o);
  quantw_k<<<256, 256, 0, stream>>>(whh, w8);
  gemm_k<1><<<dim3(64, 4),  256, 0, stream>>>(c2o,  fcw, fcb, nullptr, feat,   2048, 256,  2592);
  gemm_k<0><<<dim3(64, 16), 256, 0, stream>>>(feat, wih, bih, bhh,     gatesx, 2048, 1024, 256);
  lstm_k<<<1, 512, 0, stream>>>(gatesx, msk, h0, c0, w8, feats, out);
  heads_k<<<32, 256, 0, stream>>>(feats, pw, pb, cw, cb, out);
}

// Round 3
// 1171.704 us; speedup vs baseline: 1.5398x; 1.5398x over previous
//
#include <hip/hip_runtime.h>
#include <cstddef>

typedef __attribute__((ext_vector_type(4))) int   i32x4;
typedef __attribute__((ext_vector_type(4))) float f32x4;
typedef __attribute__((ext_vector_type(8))) short bfrag8;
typedef __attribute__((ext_vector_type(8))) unsigned short us8;

__device__ inline unsigned short f2bf(float x){
  union { float f; unsigned u; } v; v.f = x;
  unsigned r = v.u + 0x7fffu + ((v.u >> 16) & 1u);
  return (unsigned short)(r >> 16);
}
__device__ inline float bf2f(unsigned short u){
  union { unsigned u; float f; } v; v.u = ((unsigned)u) << 16; return v.f;
}
__device__ inline float fsig(float x){ return 1.f / (1.f + __expf(-x)); }
__device__ inline float ftanhf(float x){ return 2.f / (1.f + __expf(-2.f * x)) - 1.f; }

#define SW 0.30f   // int8 scale for w_hh: w = q * (SW/127)

// ---------------- conv1: [2048,4,84,84] -> relu -> bf16 [2048,16,20,20], k=8 s=4 ----------------
// anti-spill: 256-VGPR budget (512,2) + ky unroll limited to 2 (live set ~125 VGPRs)
__global__ __launch_bounds__(512, 2) void conv1_k(const float* __restrict__ obs,
                                                  const float* __restrict__ w,
                                                  const float* __restrict__ b,
                                                  unsigned short* __restrict__ out){
  __shared__ __align__(16) float s_img[28224];   // 4*84*84
  __shared__ __align__(16) float s_w[4096];      // 16*256
  __shared__ float s_b[16];
  const int n = blockIdx.x, tid = threadIdx.x;
  {
    const float4* src = (const float4*)(obs + (size_t)n * 28224);
    float4* d = (float4*)s_img;
    for (int i = tid; i < 7056; i += 512) d[i] = src[i];
    const float4* ws = (const float4*)w;
    float4* dw = (float4*)s_w;
    for (int i = tid; i < 1024; i += 512) dw[i] = ws[i];
    if (tid < 16) s_b[tid] = b[tid];
  }
  __syncthreads();
  const int lane = tid & 63, wave = tid >> 6;
  const int cg = wave & 3;   // channels 4cg..4cg+3
  const int pg = wave >> 2;  // position group 0/1
  float acc[4][4];
  #pragma unroll
  for (int r = 0; r < 4; ++r)
    #pragma unroll
    for (int c = 0; c < 4; ++c) acc[r][c] = 0.f;
  int p[4], py[4], px[4]; bool valid[4];
  #pragma unroll
  for (int r = 0; r < 4; ++r){
    int pp = pg * 64 + lane + r * 128;
    valid[r] = pp < 400;
    if (pp > 399) pp = 399;
    p[r] = pp; py[r] = pp / 20; px[r] = pp % 20;
  }
  for (int ci = 0; ci < 4; ++ci){
    #pragma unroll 2
    for (int ky = 0; ky < 8; ++ky){
      float4 wv[4][2];
      #pragma unroll
      for (int c = 0; c < 4; ++c){
        const float4* wp = (const float4*)&s_w[(cg * 4 + c) * 256 + ci * 64 + ky * 8];
        wv[c][0] = wp[0]; wv[c][1] = wp[1];
      }
      #pragma unroll
      for (int r = 0; r < 4; ++r){
        const float4* ip = (const float4*)&s_img[ci * 7056 + (4 * py[r] + ky) * 84 + 4 * px[r]];
        float4 a0 = ip[0], a1 = ip[1];
        #pragma unroll
        for (int c = 0; c < 4; ++c){
          acc[r][c] += a0.x * wv[c][0].x + a0.y * wv[c][0].y + a0.z * wv[c][0].z + a0.w * wv[c][0].w
                     + a1.x * wv[c][1].x + a1.y * wv[c][1].y + a1.z * wv[c][1].z + a1.w * wv[c][1].w;
        }
      }
    }
  }
  unsigned short* op = out + (size_t)n * 6400;
  #pragma unroll
  for (int r = 0; r < 4; ++r) if (valid[r]){
    #pragma unroll
    for (int c = 0; c < 4; ++c){
      float v = acc[r][c] + s_b[cg * 4 + c];
      op[(cg * 4 + c) * 400 + p[r]] = f2bf(v > 0.f ? v : 0.f);
    }
  }
}

// ---------------- conv2: bf16 [2048,16,20,20] -> relu -> flat bf16 [2048, 32*81], k=4 s=2 ----------------
__global__ __launch_bounds__(256, 2) void conv2_k(const unsigned short* __restrict__ in,
                                                  const float* __restrict__ w,
                                                  const float* __restrict__ b,
                                                  unsigned short* __restrict__ out){
  __shared__ __align__(16) float s_in[6400];   // 16*400
  __shared__ __align__(16) float s_w[8192];    // 32*256
  __shared__ float s_b[32];
  const int n = blockIdx.x, tid = threadIdx.x;
  {
    const us8* src = (const us8*)(in + (size_t)n * 6400);
    for (int i = tid; i < 800; i += 256){
      us8 v = src[i];
      #pragma unroll
      for (int j = 0; j < 8; ++j) s_in[i * 8 + j] = bf2f(v[j]);
    }
    const float4* ws = (const float4*)w;
    float4* dw = (float4*)s_w;
    for (int i = tid; i < 2048; i += 256) dw[i] = ws[i];
    if (tid < 32) s_b[tid] = b[tid];
  }
  __syncthreads();
  const int lane = tid & 63, wave = tid >> 6;  // wave handles channels 8w..8w+7
  float acc[2][8];
  #pragma unroll
  for (int r = 0; r < 2; ++r)
    #pragma unroll
    for (int c = 0; c < 8; ++c) acc[r][c] = 0.f;
  const int p0 = lane;
  int p1 = lane + 64; const bool v1 = p1 < 81; if (p1 > 80) p1 = 80;
  const int y0 = p0 / 9, x0 = p0 % 9, y1 = p1 / 9, x1 = p1 % 9;
  for (int ci = 0; ci < 16; ++ci){
    #pragma unroll 2
    for (int ky = 0; ky < 4; ++ky){
      float4 wv[8];
      #pragma unroll
      for (int c = 0; c < 8; ++c)
        wv[c] = *(const float4*)&s_w[(wave * 8 + c) * 256 + ci * 16 + ky * 4];
      const float2 a0  = *(const float2*)&s_in[ci * 400 + (2 * y0 + ky) * 20 + 2 * x0];
      const float2 a0b = *(const float2*)&s_in[ci * 400 + (2 * y0 + ky) * 20 + 2 * x0 + 2];
      const float2 a1  = *(const float2*)&s_in[ci * 400 + (2 * y1 + ky) * 20 + 2 * x1];
      const float2 a1b = *(const float2*)&s_in[ci * 400 + (2 * y1 + ky) * 20 + 2 * x1 + 2];
      #pragma unroll
      for (int c = 0; c < 8; ++c){
        acc[0][c] += a0.x * wv[c].x + a0.y * wv[c].y + a0b.x * wv[c].z + a0b.y * wv[c].w;
        acc[1][c] += a1.x * wv[c].x + a1.y * wv[c].y + a1b.x * wv[c].z + a1b.y * wv[c].w;
      }
    }
  }
  unsigned short* op = out + (size_t)n * 2592;
  #pragma unroll
  for (int c = 0; c < 8; ++c){
    float v0 = acc[0][c] + s_b[wave * 8 + c];
    op[(wave * 8 + c) * 81 + p0] = f2bf(v0 > 0.f ? v0 : 0.f);
    if (v1){
      float vv = acc[1][c] + s_b[wave * 8 + c];
      op[(wave * 8 + c) * 81 + p1] = f2bf(vv > 0.f ? vv : 0.f);
    }
  }
}

// ---------------- f32 -> bf16 cast (weights prep) ----------------
__global__ __launch_bounds__(256) void castbf_k(const float* __restrict__ src,
                                                unsigned short* __restrict__ dst, int n4){
  const int i = blockIdx.x * 256 + threadIdx.x;
  if (i < n4){
    float4 v = ((const float4*)src)[i];
    ushort4 o;
    o.x = f2bf(v.x); o.y = f2bf(v.y); o.z = f2bf(v.z); o.w = f2bf(v.w);
    *(ushort4*)(dst + i * 4) = o;
  }
}

// ---------------- bf16 MFMA GEMM: out[M,N] = A[M,K]bf16 @ Bw[N,K]bf16^T + bias (+relu) ----------------
// BM=BN=64, BK=32, 256 threads = 4 waves (2x2), each wave 32x32 (2x2 MFMA frags).
// LDS rows padded to 80B -> 2-way bank aliasing only (free).
template<int RELU, int OUTBF>
__global__ __launch_bounds__(256, 2) void mgemm_k(const unsigned short* __restrict__ A,
                                                  const unsigned short* __restrict__ Bw,
                                                  const float* __restrict__ bias1,
                                                  const float* __restrict__ bias2,
                                                  void* __restrict__ outp,
                                                  int N, int K){
  __shared__ __align__(16) unsigned short As[64 * 40];  // row stride 40 shorts = 80B
  __shared__ __align__(16) unsigned short Bs[64 * 40];
  const int m0 = blockIdx.x * 64, n0 = blockIdx.y * 64;
  const int tid = threadIdx.x;
  const int wave = tid >> 6, l = tid & 63;
  const int wm = wave >> 1, wn = wave & 1;
  const int fl = l & 15, fg = l >> 4;
  const int srow = tid >> 2, schunk = tid & 3;
  const unsigned short* Ag = A + (size_t)(m0 + srow) * K + schunk * 8;
  const unsigned short* Bg = Bw + (size_t)(n0 + srow) * K + schunk * 8;
  unsigned short* As_w = As + srow * 40 + schunk * 8;
  unsigned short* Bs_w = Bs + srow * 40 + schunk * 8;
  const unsigned short* Ar = As + (wm * 32 + fl) * 40 + fg * 8;
  const unsigned short* Br = Bs + (wn * 32 + fl) * 40 + fg * 8;

  f32x4 acc[2][2];
  #pragma unroll
  for (int mi = 0; mi < 2; ++mi)
    #pragma unroll
    for (int ni = 0; ni < 2; ++ni){ acc[mi][ni][0]=0.f; acc[mi][ni][1]=0.f; acc[mi][ni][2]=0.f; acc[mi][ni][3]=0.f; }

  for (int k0 = 0; k0 < K; k0 += 32){
    *(us8*)As_w = *(const us8*)(Ag + k0);
    *(us8*)Bs_w = *(const us8*)(Bg + k0);
    __syncthreads();
    bfrag8 af[2], bf[2];
    af[0] = *(const bfrag8*)(Ar);
    af[1] = *(const bfrag8*)(Ar + 16 * 40);
    bf[0] = *(const bfrag8*)(Br);
    bf[1] = *(const bfrag8*)(Br + 16 * 40);
    #pragma unroll
    for (int mi = 0; mi < 2; ++mi)
      #pragma unroll
      for (int ni = 0; ni < 2; ++ni)
        acc[mi][ni] = __builtin_amdgcn_mfma_f32_16x16x32_bf16(af[mi], bf[ni], acc[mi][ni], 0, 0, 0);
    __syncthreads();
  }

  #pragma unroll
  for (int mi = 0; mi < 2; ++mi)
    #pragma unroll
    for (int ni = 0; ni < 2; ++ni){
      const int nn = n0 + wn * 32 + ni * 16 + fl;
      const float bsum = bias1[nn] + (bias2 ? bias2[nn] : 0.f);
      #pragma unroll
      for (int q = 0; q < 4; ++q){
        const int m = m0 + wm * 32 + mi * 16 + fg * 4 + q;
        float v = acc[mi][ni][q] + bsum;
        if (RELU) v = v > 0.f ? v : 0.f;
        if (OUTBF) ((unsigned short*)outp)[(size_t)m * N + nn] = f2bf(v);
        else       ((float*)outp)[(size_t)m * N + nn] = v;
      }
    }
}

// ---------------- quantize w_hh -> int8 (packed), scale SW/127 ----------------
__global__ __launch_bounds__(256) void quantw_k(const float* __restrict__ whh,
                                                int* __restrict__ w8){
  const int i = blockIdx.x * 256 + threadIdx.x;   // one dword = 4 weights
  float4 v = ((const float4*)whh)[i];
  const float s = 127.f / SW;
  int q0 = __float2int_rn(fminf(fmaxf(v.x * s, -127.f), 127.f));
  int q1 = __float2int_rn(fminf(fmaxf(v.y * s, -127.f), 127.f));
  int q2 = __float2int_rn(fminf(fmaxf(v.z * s, -127.f), 127.f));
  int q3 = __float2int_rn(fminf(fmaxf(v.w * s, -127.f), 127.f));
  w8[i] = (q0 & 255) | ((q1 & 255) << 8) | ((q2 & 255) << 16) | ((q3 & 255) << 24);
}

// ---------------- persistent single-block LSTM scan (int8 MFMA) ---------------- (unchanged, passed R2)
__global__ __launch_bounds__(512, 2) void lstm_k(const float* __restrict__ gx,
                                                 const int* __restrict__ masks,
                                                 const float* __restrict__ h0,
                                                 const float* __restrict__ c0,
                                                 const int* __restrict__ w8,
                                                 float* __restrict__ feats,
                                                 float* __restrict__ out){
  __shared__ __align__(16) signed char h8[2][4096];   // [par][16 batches * 256 units]
  const int tid = threadIdx.x;
  const int w = tid >> 6, l = tid & 63;
  const int col = l & 15;
  const int rgrp = l >> 4;

  i32x4 Bf[4][2][4];               // [gate nt][coltile u][ks]
  #pragma unroll
  for (int nt = 0; nt < 4; ++nt)
    #pragma unroll
    for (int u = 0; u < 2; ++u){
      const int grow = nt * 256 + u * 128 + (w << 4) + col;
      #pragma unroll
      for (int ks = 0; ks < 4; ++ks)
        Bf[nt][u][ks] = *(const i32x4*)(w8 + grow * 64 + ks * 16 + rgrp * 4);
    }

  float c[2][4];
  float gxr[2][4][4];              // [u][nt][r]
  float mnext[4];
  const unsigned jlo = (w << 4) + col;
  const float* gxw = gx + jlo;
  #pragma unroll
  for (int r = 0; r < 4; ++r){
    const int b = (rgrp << 2) + r;
    const float m0 = (float)masks[b * 128];
    mnext[r] = (float)masks[b * 128 + 1];
    #pragma unroll
    for (int u = 0; u < 2; ++u){
      const int j = u * 128 + jlo;
      const float hv = h0[b * 256 + j] * m0;
      c[u][r] = c0[b * 256 + j] * m0;
      int q = __float2int_rn(fminf(fmaxf(hv * 127.f, -127.f), 127.f));
      h8[0][b * 256 + (j ^ ((b & 7) << 4))] = (signed char)q;
      #pragma unroll
      for (int nt = 0; nt < 4; ++nt)
        gxr[u][nt][r] = gxw[(unsigned)b * 131072u + nt * 256 + u * 128];
    }
  }
  __syncthreads();

  const float S = (SW / 127.f) * (1.f / 127.f);
  for (int t = 0; t < 128; ++t){
    const int par = t & 1;
    i32x4 Af[4];
    const signed char* hb = &h8[par][0];
    const int row = col;
    #pragma unroll
    for (int ks = 0; ks < 4; ++ks){
      const int k0 = ks * 64 + rgrp * 16;
      Af[ks] = *(const i32x4*)(hb + row * 256 + (k0 ^ ((row & 7) << 4)));
    }
    i32x4 acc[2][4];
    #pragma unroll
    for (int u = 0; u < 2; ++u)
      #pragma unroll
      for (int nt = 0; nt < 4; ++nt){
        acc[u][nt][0] = 0; acc[u][nt][1] = 0; acc[u][nt][2] = 0; acc[u][nt][3] = 0;
        #pragma unroll
        for (int ks = 0; ks < 4; ++ks)
          acc[u][nt] = __builtin_amdgcn_mfma_i32_16x16x64_i8(Af[ks], Bf[nt][u][ks], acc[u][nt], 0, 0, 0);
      }
    float mcur[4];
    #pragma unroll
    for (int r = 0; r < 4; ++r) mcur[r] = mnext[r];
    #pragma unroll
    for (int r = 0; r < 4; ++r){
      const int b = (rgrp << 2) + r;
      const float mn = (t < 127) ? mcur[r] : 1.f;
      #pragma unroll
      for (int u = 0; u < 2; ++u){
        const int j = u * 128 + jlo;
        const float gi = (float)acc[u][0][r] * S + gxr[u][0][r];
        const float gf = (float)acc[u][1][r] * S + gxr[u][1][r];
        const float gg = (float)acc[u][2][r] * S + gxr[u][2][r];
        const float go = (float)acc[u][3][r] * S + gxr[u][3][r];
        const float iv = fsig(gi), fv = fsig(gf), gv = ftanhf(gg), ov = fsig(go);
        const float cn = fv * c[u][r] + iv * gv;
        const float hn = ov * ftanhf(cn);
        feats[((size_t)b * 128 + t) * 256 + j] = hn;
        if (t == 127){
          out[38912 + b * 256 + j] = hn;
          out[43008 + b * 256 + j] = cn;
        }
        c[u][r] = cn * mn;
        const float hm = hn * mn;
        int q = __float2int_rn(fminf(fmaxf(hm * 127.f, -127.f), 127.f));
        h8[par ^ 1][b * 256 + (j ^ ((b & 7) << 4))] = (signed char)q;
      }
    }
    if (t < 127){
      #pragma unroll
      for (int r = 0; r < 4; ++r){
        const int b = (rgrp << 2) + r;
        if (t < 126) mnext[r] = (float)masks[b * 128 + t + 2]; else mnext[r] = 1.f;
        const unsigned off = (unsigned)b * 131072u + (unsigned)(t + 1) * 1024u;
        #pragma unroll
        for (int u = 0; u < 2; ++u)
          #pragma unroll
          for (int nt = 0; nt < 4; ++nt)
            gxr[u][nt][r] = gxw[off + nt * 256 + u * 128];
      }
    }
    __syncthreads();
  }
}

// ---------------- heads: feats[2048,256] -> policy[2048,18], critic[2048,1] ----------------
__global__ __launch_bounds__(256) void heads_k(const float* __restrict__ feats,
                                               const float* __restrict__ pw,
                                               const float* __restrict__ pb,
                                               const float* __restrict__ cw,
                                               const float* __restrict__ cb,
                                               float* __restrict__ out){
  __shared__ float sf[64][257];
  __shared__ float swt[19][256];
  const int tid = threadIdx.x;
  const int nb = blockIdx.x * 64;
  {
    const float4* src = (const float4*)(feats + (size_t)nb * 256);
    for (int i = tid; i < 4096; i += 256){
      int rr = i >> 6, cc = (i & 63) * 4;
      float4 v = src[i];
      sf[rr][cc] = v.x; sf[rr][cc + 1] = v.y; sf[rr][cc + 2] = v.z; sf[rr][cc + 3] = v.w;
    }
    for (int i = tid; i < 1152; i += 256){
      int pp = i >> 6, cc = (i & 63) * 4;
      float4 v = ((const float4*)pw)[i];
      swt[pp][cc] = v.x; swt[pp][cc + 1] = v.y; swt[pp][cc + 2] = v.z; swt[pp][cc + 3] = v.w;
    }
    if (tid < 64){
      float4 v = ((const float4*)cw)[tid];
      int cc = tid * 4;
      swt[18][cc] = v.x; swt[18][cc + 1] = v.y; swt[18][cc + 2] = v.z; swt[18][cc + 3] = v.w;
    }
  }
  __syncthreads();
  const int n = tid & 63, pg = tid >> 6;
  float acc[5] = {0.f, 0.f, 0.f, 0.f, 0.f};
  for (int k = 0; k < 256; ++k){
    const float a = sf[n][k];
    #pragma unroll
    for (int q = 0; q < 5; ++q){
      const int p = pg + q * 4;
      if (p < 19) acc[q] += a * swt[p][k];
    }
  }
  #pragma unroll
  for (int q = 0; q < 5; ++q){
    const int p = pg + q * 4;
    if (p < 18){
      out[(size_t)(nb + n) * 18 + p] = acc[q] + pb[p];
    } else if (p == 18){
      out[36864 + nb + n] = acc[q] + cb[0];
    }
  }
}

extern "C" void kernel_launch(void* const* d_in, const int* in_sizes, int n_in,
                              void* d_out, int out_size, void* d_ws, size_t ws_size,
                              hipStream_t stream) {
  const float* obs  = (const float*)d_in[0];
  const int*   msk  = (const int*)d_in[1];
  const float* h0   = (const float*)d_in[2];
  const float* c0   = (const float*)d_in[3];
  const float* w1   = (const float*)d_in[4];
  const float* b1   = (const float*)d_in[5];
  const float* w2   = (const float*)d_in[6];
  const float* b2   = (const float*)d_in[7];
  const float* fcw  = (const float*)d_in[8];
  const float* fcb  = (const float*)d_in[9];
  const float* wih  = (const float*)d_in[10];
  const float* whh  = (const float*)d_in[11];
  const float* bih  = (const float*)d_in[12];
  const float* bhh  = (const float*)d_in[13];
  const float* pw   = (const float*)d_in[14];
  const float* pb   = (const float*)d_in[15];
  const float* cw   = (const float*)d_in[16];
  const float* cb   = (const float*)d_in[17];
  float* out = (float*)d_out;
  float* ws  = (float*)d_ws;

  // workspace (float offsets). Peak = c1o + c2o = 9,207,808 floats (36.8 MB).
  // c1o region [0, 6,553,600) is DEAD after conv2 and is reused (stream-ordered).
  unsigned short* c1o    = (unsigned short*)ws;             // bf16 2048*6400
  unsigned short* c2o    = (unsigned short*)(ws + 6553600); // bf16 2048*2592
  unsigned short* fcw_bf = (unsigned short*)ws;                    // 663,552 bf16 @ 0
  unsigned short* wih_bf = (unsigned short*)(ws + 331776);         // 262,144 bf16
  unsigned short* feat   = (unsigned short*)(ws + 462848);         // bf16 2048*256
  float*          gatesx = ws + 724992;                            // fp32 2048*1024
  float*          feats  = ws + 2822144;                           // fp32 2048*256
  int*            w8     = (int*)(ws + 3346432);                   // 65,536 dwords

  conv1_k<<<2048, 512, 0, stream>>>(obs, w1, b1, c1o);
  conv2_k<<<2048, 256, 0, stream>>>(c1o, w2, b2, c2o);
  // weight preps (write into dead c1o region -> must follow conv2)
  castbf_k<<<648, 256, 0, stream>>>(fcw, fcw_bf, 165888);
  castbf_k<<<256, 256, 0, stream>>>(wih, wih_bf, 65536);
  quantw_k<<<256, 256, 0, stream>>>(whh, w8);
  // fc: [2048,2592] @ [256,2592]^T -> relu -> bf16 feat
  mgemm_k<1,1><<<dim3(32, 4),  256, 0, stream>>>(c2o,  fcw_bf, fcb, nullptr, feat,   256,  2592);
  // gates: [2048,256] @ [1024,256]^T + (bih+bhh) -> fp32 gatesx
  mgemm_k<0,0><<<dim3(32, 16), 256, 0, stream>>>(feat, wih_bf, bih, bhh,     gatesx, 1024, 256);
  lstm_k<<<1, 512, 0, stream>>>(gatesx, msk, h0, c0, w8, feats, out);
  heads_k<<<32, 256, 0, stream>>>(feats, pw, pb, cw, cb, out);
}

// Round 5
// 815.599 us; speedup vs baseline: 2.2121x; 1.4366x over previous
//
#include <hip/hip_runtime.h>
#include <cstddef>

typedef __attribute__((ext_vector_type(4))) int   i32x4;
typedef __attribute__((ext_vector_type(4))) float f32x4;
typedef __attribute__((ext_vector_type(8))) short bfrag8;
typedef __attribute__((ext_vector_type(8))) unsigned short us8;

__device__ inline unsigned short f2bf(float x){
  union { float f; unsigned u; } v; v.f = x;
  unsigned r = v.u + 0x7fffu + ((v.u >> 16) & 1u);
  return (unsigned short)(r >> 16);
}
__device__ inline float bf2f(unsigned short u){
  union { unsigned u; float f; } v; v.u = ((unsigned)u) << 16; return v.f;
}
__device__ inline float fsig(float x){ return 1.f / (1.f + __expf(-x)); }
__device__ inline float ftanhf(float x){ return 2.f / (1.f + __expf(-2.f * x)) - 1.f; }

#define SW 0.30f   // int8 scale for w_hh: w = q * (SW/127)

// ---------------- conv1: [2048,4,84,84] -> relu -> bf16 [2048,16,20,20], k=8 s=4 ----------------
// LDS: image staged 2 channels at a time (56.4 KB) + weights 16 KB = 72.9 KB -> 2 blocks/CU.
// Accumulators live in registers across the re-stage; arithmetic identical to 1-stage version.
__global__ __launch_bounds__(512, 2) void conv1_k(const float* __restrict__ obs,
                                                  const float* __restrict__ w,
                                                  const float* __restrict__ b,
                                                  unsigned short* __restrict__ out){
  __shared__ __align__(16) float s_img[14112];   // 2*84*84
  __shared__ __align__(16) float s_w[4096];      // 16*256
  __shared__ float s_b[16];
  const int n = blockIdx.x, tid = threadIdx.x;
  {
    const float4* ws = (const float4*)w;
    float4* dw = (float4*)s_w;
    for (int i = tid; i < 1024; i += 512) dw[i] = ws[i];
    if (tid < 16) s_b[tid] = b[tid];
  }
  const int lane = tid & 63, wave = tid >> 6;
  const int cg = wave & 3;   // channels 4cg..4cg+3
  const int pg = wave >> 2;  // position group 0/1
  float acc[4][4];
  #pragma unroll
  for (int r = 0; r < 4; ++r)
    #pragma unroll
    for (int c = 0; c < 4; ++c) acc[r][c] = 0.f;
  int p[4], py[4], px[4]; bool valid[4];
  #pragma unroll
  for (int r = 0; r < 4; ++r){
    int pp = pg * 64 + lane + r * 128;
    valid[r] = pp < 400;
    if (pp > 399) pp = 399;
    p[r] = pp; py[r] = pp / 20; px[r] = pp % 20;
  }
  for (int cp = 0; cp < 2; ++cp){          // channel pair 2cp, 2cp+1
    __syncthreads();                        // prior reads done (cp=0: no-op ordering for s_w)
    {
      const float4* src = (const float4*)(obs + (size_t)n * 28224 + cp * 14112);
      float4* d = (float4*)s_img;
      for (int i = tid; i < 3528; i += 512) d[i] = src[i];
    }
    __syncthreads();
    for (int ci = 0; ci < 2; ++ci){
      const int cw_ = cp * 2 + ci;          // weight channel index
      #pragma unroll 2
      for (int ky = 0; ky < 8; ++ky){
        float4 wv[4][2];
        #pragma unroll
        for (int c = 0; c < 4; ++c){
          const float4* wp = (const float4*)&s_w[(cg * 4 + c) * 256 + cw_ * 64 + ky * 8];
          wv[c][0] = wp[0]; wv[c][1] = wp[1];
        }
        #pragma unroll
        for (int r = 0; r < 4; ++r){
          const float4* ip = (const float4*)&s_img[ci * 7056 + (4 * py[r] + ky) * 84 + 4 * px[r]];
          float4 a0 = ip[0], a1 = ip[1];
          #pragma unroll
          for (int c = 0; c < 4; ++c){
            acc[r][c] += a0.x * wv[c][0].x + a0.y * wv[c][0].y + a0.z * wv[c][0].z + a0.w * wv[c][0].w
                       + a1.x * wv[c][1].x + a1.y * wv[c][1].y + a1.z * wv[c][1].z + a1.w * wv[c][1].w;
          }
        }
      }
    }
  }
  unsigned short* op = out + (size_t)n * 6400;
  #pragma unroll
  for (int r = 0; r < 4; ++r) if (valid[r]){
    #pragma unroll
    for (int c = 0; c < 4; ++c){
      float v = acc[r][c] + s_b[cg * 4 + c];
      op[(cg * 4 + c) * 400 + p[r]] = f2bf(v > 0.f ? v : 0.f);
    }
  }
}

// ---------------- conv2: bf16 [2048,16,20,20] -> relu -> flat bf16 [2048, 32*81], k=4 s=2 ----------------
__global__ __launch_bounds__(256, 2) void conv2_k(const unsigned short* __restrict__ in,
                                                  const float* __restrict__ w,
                                                  const float* __restrict__ b,
                                                  unsigned short* __restrict__ out){
  __shared__ __align__(16) float s_in[6400];   // 16*400
  __shared__ __align__(16) float s_w[8192];    // 32*256
  __shared__ float s_b[32];
  const int n = blockIdx.x, tid = threadIdx.x;
  {
    const us8* src = (const us8*)(in + (size_t)n * 6400);
    for (int i = tid; i < 800; i += 256){
      us8 v = src[i];
      #pragma unroll
      for (int j = 0; j < 8; ++j) s_in[i * 8 + j] = bf2f(v[j]);
    }
    const float4* ws = (const float4*)w;
    float4* dw = (float4*)s_w;
    for (int i = tid; i < 2048; i += 256) dw[i] = ws[i];
    if (tid < 32) s_b[tid] = b[tid];
  }
  __syncthreads();
  const int lane = tid & 63, wave = tid >> 6;  // wave handles channels 8w..8w+7
  float acc[2][8];
  #pragma unroll
  for (int r = 0; r < 2; ++r)
    #pragma unroll
    for (int c = 0; c < 8; ++c) acc[r][c] = 0.f;
  const int p0 = lane;
  int p1 = lane + 64; const bool v1 = p1 < 81; if (p1 > 80) p1 = 80;
  const int y0 = p0 / 9, x0 = p0 % 9, y1 = p1 / 9, x1 = p1 % 9;
  for (int ci = 0; ci < 16; ++ci){
    #pragma unroll 2
    for (int ky = 0; ky < 4; ++ky){
      float4 wv[8];
      #pragma unroll
      for (int c = 0; c < 8; ++c)
        wv[c] = *(const float4*)&s_w[(wave * 8 + c) * 256 + ci * 16 + ky * 4];
      const float2 a0  = *(const float2*)&s_in[ci * 400 + (2 * y0 + ky) * 20 + 2 * x0];
      const float2 a0b = *(const float2*)&s_in[ci * 400 + (2 * y0 + ky) * 20 + 2 * x0 + 2];
      const float2 a1  = *(const float2*)&s_in[ci * 400 + (2 * y1 + ky) * 20 + 2 * x1];
      const float2 a1b = *(const float2*)&s_in[ci * 400 + (2 * y1 + ky) * 20 + 2 * x1 + 2];
      #pragma unroll
      for (int c = 0; c < 8; ++c){
        acc[0][c] += a0.x * wv[c].x + a0.y * wv[c].y + a0b.x * wv[c].z + a0b.y * wv[c].w;
        acc[1][c] += a1.x * wv[c].x + a1.y * wv[c].y + a1b.x * wv[c].z + a1b.y * wv[c].w;
      }
    }
  }
  unsigned short* op = out + (size_t)n * 2592;
  #pragma unroll
  for (int c = 0; c < 8; ++c){
    float v0 = acc[0][c] + s_b[wave * 8 + c];
    op[(wave * 8 + c) * 81 + p0] = f2bf(v0 > 0.f ? v0 : 0.f);
    if (v1){
      float vv = acc[1][c] + s_b[wave * 8 + c];
      op[(wave * 8 + c) * 81 + p1] = f2bf(vv > 0.f ? vv : 0.f);
    }
  }
}

// ---------------- f32 -> bf16 cast (weights prep) ----------------
__global__ __launch_bounds__(256) void castbf_k(const float* __restrict__ src,
                                                unsigned short* __restrict__ dst, int n4){
  const int i = blockIdx.x * 256 + threadIdx.x;
  if (i < n4){
    float4 v = ((const float4*)src)[i];
    ushort4 o;
    o.x = f2bf(v.x); o.y = f2bf(v.y); o.z = f2bf(v.z); o.w = f2bf(v.w);
    *(ushort4*)(dst + i * 4) = o;
  }
}

// ---------------- bf16 MFMA GEMM: out[M,N] = A[M,K]bf16 @ Bw[N,K]bf16^T + bias (+relu) ----------------
template<int RELU, int OUTBF>
__global__ __launch_bounds__(256, 2) void mgemm_k(const unsigned short* __restrict__ A,
                                                  const unsigned short* __restrict__ Bw,
                                                  const float* __restrict__ bias1,
                                                  const float* __restrict__ bias2,
                                                  void* __restrict__ outp,
                                                  int N, int K){
  __shared__ __align__(16) unsigned short As[64 * 40];  // row stride 40 shorts = 80B
  __shared__ __align__(16) unsigned short Bs[64 * 40];
  const int m0 = blockIdx.x * 64, n0 = blockIdx.y * 64;
  const int tid = threadIdx.x;
  const int wave = tid >> 6, l = tid & 63;
  const int wm = wave >> 1, wn = wave & 1;
  const int fl = l & 15, fg = l >> 4;
  const int srow = tid >> 2, schunk = tid & 3;
  const unsigned short* Ag = A + (size_t)(m0 + srow) * K + schunk * 8;
  const unsigned short* Bg = Bw + (size_t)(n0 + srow) * K + schunk * 8;
  unsigned short* As_w = As + srow * 40 + schunk * 8;
  unsigned short* Bs_w = Bs + srow * 40 + schunk * 8;
  const unsigned short* Ar = As + (wm * 32 + fl) * 40 + fg * 8;
  const unsigned short* Br = Bs + (wn * 32 + fl) * 40 + fg * 8;

  f32x4 acc[2][2];
  #pragma unroll
  for (int mi = 0; mi < 2; ++mi)
    #pragma unroll
    for (int ni = 0; ni < 2; ++ni){ acc[mi][ni][0]=0.f; acc[mi][ni][1]=0.f; acc[mi][ni][2]=0.f; acc[mi][ni][3]=0.f; }

  for (int k0 = 0; k0 < K; k0 += 32){
    *(us8*)As_w = *(const us8*)(Ag + k0);
    *(us8*)Bs_w = *(const us8*)(Bg + k0);
    __syncthreads();
    bfrag8 af[2], bf[2];
    af[0] = *(const bfrag8*)(Ar);
    af[1] = *(const bfrag8*)(Ar + 16 * 40);
    bf[0] = *(const bfrag8*)(Br);
    bf[1] = *(const bfrag8*)(Br + 16 * 40);
    #pragma unroll
    for (int mi = 0; mi < 2; ++mi)
      #pragma unroll
      for (int ni = 0; ni < 2; ++ni)
        acc[mi][ni] = __builtin_amdgcn_mfma_f32_16x16x32_bf16(af[mi], bf[ni], acc[mi][ni], 0, 0, 0);
    __syncthreads();
  }

  #pragma unroll
  for (int mi = 0; mi < 2; ++mi)
    #pragma unroll
    for (int ni = 0; ni < 2; ++ni){
      const int nn = n0 + wn * 32 + ni * 16 + fl;
      const float bsum = bias1[nn] + (bias2 ? bias2[nn] : 0.f);
      #pragma unroll
      for (int q = 0; q < 4; ++q){
        const int m = m0 + wm * 32 + mi * 16 + fg * 4 + q;
        float v = acc[mi][ni][q] + bsum;
        if (RELU) v = v > 0.f ? v : 0.f;
        if (OUTBF) ((unsigned short*)outp)[(size_t)m * N + nn] = f2bf(v);
        else       ((float*)outp)[(size_t)m * N + nn] = v;
      }
    }
}

// ---------------- quantize w_hh -> int8 (packed), scale SW/127 ----------------
__global__ __launch_bounds__(256) void quantw_k(const float* __restrict__ whh,
                                                int* __restrict__ w8){
  const int i = blockIdx.x * 256 + threadIdx.x;   // one dword = 4 weights
  float4 v = ((const float4*)whh)[i];
  const float s = 127.f / SW;
  int q0 = __float2int_rn(fminf(fmaxf(v.x * s, -127.f), 127.f));
  int q1 = __float2int_rn(fminf(fmaxf(v.y * s, -127.f), 127.f));
  int q2 = __float2int_rn(fminf(fmaxf(v.z * s, -127.f), 127.f));
  int q3 = __float2int_rn(fminf(fmaxf(v.w * s, -127.f), 127.f));
  w8[i] = (q0 & 255) | ((q1 & 255) << 8) | ((q2 & 255) << 16) | ((q3 & 255) << 24);
}

// ---------------- batch-parallel LSTM scan: 16 blocks, one batch element each ----------------
// 512 threads = 8 waves/block. Wave w owns hidden units 32w..32w+31 (unit-tiles 2w, 2w+1)
// for all 4 gates. W_hh int8 B-fragments in registers (128 VGPRs/lane). The 1x256 matvec
// rides mfma_i32_16x16x64_i8 with broadcast-A (A[m][k] = h[k] for all m -> every C row
// equals the matvec; lane layouts identical to the validated batch-major version).
// h passes through a tiny 256B LDS ping-pong; c, gx stay in registers.
__global__ __launch_bounds__(512, 2) void lstm_k(const float* __restrict__ gx,
                                                 const int* __restrict__ masks,
                                                 const float* __restrict__ h0,
                                                 const float* __restrict__ c0,
                                                 const int* __restrict__ w8,
                                                 float* __restrict__ feats,
                                                 float* __restrict__ out){
  __shared__ __align__(16) signed char h8[2][256];
  const int b = blockIdx.x;
  const int tid = threadIdx.x;
  const int w = tid >> 6, l = tid & 63;
  const int col = l & 15;          // unit-within-tile / MFMA n-col
  const int rgrp = l >> 4;         // k-slice selector within 64-k step

  // --- B-fragments: B[k][n] = w8row[grow][k]; grow = g4*256 + (2w+uu)*16 + col ---
  i32x4 Bf[4][2][4];               // [gate g4][unit-tile uu][ks]
  #pragma unroll
  for (int g4 = 0; g4 < 4; ++g4)
    #pragma unroll
    for (int uu = 0; uu < 2; ++uu){
      const int grow = g4 * 256 + (2 * w + uu) * 16 + col;
      #pragma unroll
      for (int ks = 0; ks < 4; ++ks)
        Bf[g4][uu][ks] = *(const i32x4*)(w8 + grow * 64 + ks * 16 + rgrp * 4);
    }

  // --- state init ---
  const float* gxb = gx + (size_t)b * 131072;
  float c[2];
  float gxr[4][2];
  const float m0 = (float)masks[b * 128];
  float mnext = (float)masks[b * 128 + 1];
  #pragma unroll
  for (int uu = 0; uu < 2; ++uu){
    const int j = (2 * w + uu) * 16 + col;
    c[uu] = c0[b * 256 + j] * m0;
    const float hv = h0[b * 256 + j] * m0;
    if (l < 16){
      int q = __float2int_rn(fminf(fmaxf(hv * 127.f, -127.f), 127.f));
      h8[0][j] = (signed char)q;
    }
    #pragma unroll
    for (int g4 = 0; g4 < 4; ++g4)
      gxr[g4][uu] = gxb[g4 * 256 + (2 * w + uu) * 16 + col];
  }
  __syncthreads();

  const float S = (SW / 127.f) * (1.f / 127.f);
  for (int t = 0; t < 128; ++t){
    const int par = t & 1;
    // broadcast-A fragments: A[m][k] = h[k], k = ks*64 + rgrp*16 + i
    i32x4 Af[4];
    #pragma unroll
    for (int ks = 0; ks < 4; ++ks)
      Af[ks] = *(const i32x4*)&h8[par][ks * 64 + rgrp * 16];
    i32x4 acc[4][2];
    #pragma unroll
    for (int g4 = 0; g4 < 4; ++g4)
      #pragma unroll
      for (int uu = 0; uu < 2; ++uu){
        acc[g4][uu][0] = 0; acc[g4][uu][1] = 0; acc[g4][uu][2] = 0; acc[g4][uu][3] = 0;
        #pragma unroll
        for (int ks = 0; ks < 4; ++ks)
          acc[g4][uu] = __builtin_amdgcn_mfma_i32_16x16x64_i8(Af[ks], Bf[g4][uu][ks], acc[g4][uu], 0, 0, 0);
      }
    // prefetch gx and mask for t+1 (hidden under this step's MFMA+elementwise)
    float gxn[4][2];
    float mnext2 = 1.f;
    if (t < 127){
      const float* g1 = gxb + (size_t)(t + 1) * 1024;
      #pragma unroll
      for (int g4 = 0; g4 < 4; ++g4)
        #pragma unroll
        for (int uu = 0; uu < 2; ++uu)
          gxn[g4][uu] = g1[g4 * 256 + (2 * w + uu) * 16 + col];
      if (t < 126) mnext2 = (float)masks[b * 128 + t + 2];
    }
    const float mn = (t < 127) ? mnext : 1.f;
    #pragma unroll
    for (int uu = 0; uu < 2; ++uu){
      const int j = (2 * w + uu) * 16 + col;
      const float gi = (float)acc[0][uu][0] * S + gxr[0][uu];
      const float gf = (float)acc[1][uu][0] * S + gxr[1][uu];
      const float gg = (float)acc[2][uu][0] * S + gxr[2][uu];
      const float go = (float)acc[3][uu][0] * S + gxr[3][uu];
      const float iv = fsig(gi), fv = fsig(gf), gv = ftanhf(gg), ov = fsig(go);
      const float cn = fv * c[uu] + iv * gv;
      const float hn = ov * ftanhf(cn);
      if (l < 16){
        feats[((size_t)b * 128 + t) * 256 + j] = hn;
        if (t == 127){
          out[38912 + b * 256 + j] = hn;
          out[43008 + b * 256 + j] = cn;
        }
        const float hm = hn * mn;
        int q = __float2int_rn(fminf(fmaxf(hm * 127.f, -127.f), 127.f));
        h8[par ^ 1][j] = (signed char)q;
      }
      c[uu] = cn * mn;
    }
    #pragma unroll
    for (int g4 = 0; g4 < 4; ++g4)
      #pragma unroll
      for (int uu = 0; uu < 2; ++uu)
        gxr[g4][uu] = gxn[g4][uu];
    mnext = mnext2;
    __syncthreads();
  }
}

// ---------------- heads: feats[2048,256] -> policy[2048,18], critic[2048,1] ----------------
__global__ __launch_bounds__(256) void heads_k(const float* __restrict__ feats,
                                               const float* __restrict__ pw,
                                               const float* __restrict__ pb,
                                               const float* __restrict__ cw,
                                               const float* __restrict__ cb,
                                               float* __restrict__ out){
  __shared__ float sf[64][257];
  __shared__ float swt[19][256];
  const int tid = threadIdx.x;
  const int nb = blockIdx.x * 64;
  {
    const float4* src = (const float4*)(feats + (size_t)nb * 256);
    for (int i = tid; i < 4096; i += 256){
      int rr = i >> 6, cc = (i & 63) * 4;
      float4 v = src[i];
      sf[rr][cc] = v.x; sf[rr][cc + 1] = v.y; sf[rr][cc + 2] = v.z; sf[rr][cc + 3] = v.w;
    }
    for (int i = tid; i < 1152; i += 256){
      int pp = i >> 6, cc = (i & 63) * 4;
      float4 v = ((const float4*)pw)[i];
      swt[pp][cc] = v.x; swt[pp][cc + 1] = v.y; swt[pp][cc + 2] = v.z; swt[pp][cc + 3] = v.w;
    }
    if (tid < 64){
      float4 v = ((const float4*)cw)[tid];
      int cc = tid * 4;
      swt[18][cc] = v.x; swt[18][cc + 1] = v.y; swt[18][cc + 2] = v.z; swt[18][cc + 3] = v.w;
    }
  }
  __syncthreads();
  const int n = tid & 63, pg = tid >> 6;
  float acc[5] = {0.f, 0.f, 0.f, 0.f, 0.f};
  for (int k = 0; k < 256; ++k){
    const float a = sf[n][k];
    #pragma unroll
    for (int q = 0; q < 5; ++q){
      const int p = pg + q * 4;
      if (p < 19) acc[q] += a * swt[p][k];
    }
  }
  #pragma unroll
  for (int q = 0; q < 5; ++q){
    const int p = pg + q * 4;
    if (p < 18){
      out[(size_t)(nb + n) * 18 + p] = acc[q] + pb[p];
    } else if (p == 18){
      out[36864 + nb + n] = acc[q] + cb[0];
    }
  }
}

extern "C" void kernel_launch(void* const* d_in, const int* in_sizes, int n_in,
                              void* d_out, int out_size, void* d_ws, size_t ws_size,
                              hipStream_t stream) {
  const float* obs  = (const float*)d_in[0];
  const int*   msk  = (const int*)d_in[1];
  const float* h0   = (const float*)d_in[2];
  const float* c0   = (const float*)d_in[3];
  const float* w1   = (const float*)d_in[4];
  const float* b1   = (const float*)d_in[5];
  const float* w2   = (const float*)d_in[6];
  const float* b2   = (const float*)d_in[7];
  const float* fcw  = (const float*)d_in[8];
  const float* fcb  = (const float*)d_in[9];
  const float* wih  = (const float*)d_in[10];
  const float* whh  = (const float*)d_in[11];
  const float* bih  = (const float*)d_in[12];
  const float* bhh  = (const float*)d_in[13];
  const float* pw   = (const float*)d_in[14];
  const float* pb   = (const float*)d_in[15];
  const float* cw   = (const float*)d_in[16];
  const float* cb   = (const float*)d_in[17];
  float* out = (float*)d_out;
  float* ws  = (float*)d_ws;

  // workspace (float offsets). Peak = c1o + c2o = 9,207,808 floats (36.8 MB).
  // c1o region [0, 6,553,600) is DEAD after conv2 and is reused (stream-ordered).
  unsigned short* c1o    = (unsigned short*)ws;             // bf16 2048*6400
  unsigned short* c2o    = (unsigned short*)(ws + 6553600); // bf16 2048*2592
  unsigned short* fcw_bf = (unsigned short*)ws;                    // 663,552 bf16 @ 0
  unsigned short* wih_bf = (unsigned short*)(ws + 331776);         // 262,144 bf16
  unsigned short* feat   = (unsigned short*)(ws + 462848);         // bf16 2048*256
  float*          gatesx = ws + 724992;                            // fp32 2048*1024
  float*          feats  = ws + 2822144;                           // fp32 2048*256
  int*            w8     = (int*)(ws + 3346432);                   // 65,536 dwords

  conv1_k<<<2048, 512, 0, stream>>>(obs, w1, b1, c1o);
  conv2_k<<<2048, 256, 0, stream>>>(c1o, w2, b2, c2o);
  // weight preps (write into dead c1o region -> must follow conv2)
  castbf_k<<<648, 256, 0, stream>>>(fcw, fcw_bf, 165888);
  castbf_k<<<256, 256, 0, stream>>>(wih, wih_bf, 65536);
  quantw_k<<<256, 256, 0, stream>>>(whh, w8);
  // fc: [2048,2592] @ [256,2592]^T -> relu -> bf16 feat
  mgemm_k<1,1><<<dim3(32, 4),  256, 0, stream>>>(c2o,  fcw_bf, fcb, nullptr, feat,   256,  2592);
  // gates: [2048,256] @ [1024,256]^T + (bih+bhh) -> fp32 gatesx
  mgemm_k<0,0><<<dim3(32, 16), 256, 0, stream>>>(feat, wih_bf, bih, bhh,     gatesx, 1024, 256);
  lstm_k<<<16, 512, 0, stream>>>(gatesx, msk, h0, c0, w8, feats, out);
  heads_k<<<32, 256, 0, stream>>>(feats, pw, pb, cw, cb, out);
}